// Round 8
// baseline (477.809 us; speedup 1.0000x reference)
//
#include <hip/hip_runtime.h>

// TemporalContrastiveLoss: B=512, T=256, D=256, temperature 0.1.
// Grid = 512 blocks (2/CU -- TLP to hide LDS/load latency), 1 batch/block.
// Per batch: S_raw = X*X^T accumulated over 4 K-chunks (64 cols each).
// K-chunk pipeline (double-buffered 32 KB LDS chunk):
//   iter g: {vmwait(counted); cast fp32->bf16; swizzled LDS write chunk g} ;
//           {issue global loads chunk g+1} ; RAW barrier ; {MFMA chunk g}.
// Raw s_barrier + lgkmcnt(0) only (keeps prefetch loads in flight).
// Epilogue: inv=rsqrt(diag) from diagonal tiles, scaled exp column-sums
// (symmetric row==col sum), fixed max=10, super-diagonal target,
// per-batch partial. K3: 512->1 mean.

typedef float f32x4  __attribute__((ext_vector_type(4)));
typedef float f32x16 __attribute__((ext_vector_type(16)));
typedef unsigned int u32x2 __attribute__((ext_vector_type(2)));
typedef unsigned int u32x4 __attribute__((ext_vector_type(4)));
typedef __bf16 bf16x8 __attribute__((ext_vector_type(8)));

#define NB 512
#define NT 256
#define ND 256
#define K10L2E 14.42695041f   // 10 * log2(e)

#define MFMA32 __builtin_amdgcn_mfma_f32_32x32x16_bf16

__device__ __forceinline__ unsigned int f2bf_rne(float f) {
  unsigned int u = __float_as_uint(f);
  return (u + 0x7fffu + ((u >> 16) & 1u)) >> 16;
}

// Workgroup barrier that does NOT drain vmcnt: drain own LDS ops
// (lgkmcnt) for cross-wave visibility, then raw s_barrier. Global
// prefetch loads stay in flight across it (unlike __syncthreads).
__device__ __forceinline__ void wg_barrier() {
  asm volatile("s_waitcnt lgkmcnt(0)" ::: "memory");
  __builtin_amdgcn_s_barrier();
  asm volatile("" ::: "memory");
}

// LDS chunk layout: [256 rows][8 slots of 16B], slot = c ^ (row&7)
// (byte ^= (row&7)<<4): spreads the stride-128B column reads across banks.
__global__ __launch_bounds__(512, 4) void fused_kernel(
    const float* __restrict__ x, float* __restrict__ partial) {
  __shared__ u32x4 ck[2 * NT * 8];   // 2 x 32 KiB K-chunk double buffer
  __shared__ float invbuf[NT];       // 1/||x_r|| from MFMA diagonal
  __shared__ float sbuf[NT][5];      // per-col, per-64row-group sum exp(p-10)
  __shared__ float tbuf[NT];         // per-row target logit (x10, normalized)
  __shared__ float redbuf[8];

  const int t    = threadIdx.x;
  const int wave = t >> 6;
  const int lane = t & 63;
  const int lo5  = lane & 31;
  const int hi   = lane >> 5;
  const int sx6  = lo5 & 6;          // (lo5&7)&6
  const int hx   = hi ^ (lo5 & 1);

  // tile assignment: wave w -> tiles (tr, tcA), (tr, tcB); w<4 has diag in A
  const int d   = wave >> 2;
  const int tr  = wave & 3;
  const int tcA = (tr + d) & 3;
  const int tcB = (tr + d + 2) & 3;
  const int R  = tr * 64, CA = tcA * 64, CB = tcB * 64;

  // staging assignment: wave covers rows wave*32..+31, 64 cols per chunk
  const int lrow = lane >> 4;        // 0..3
  const int lcol = lane & 15;        // f32x4 index within 64-col chunk
  const int srow = wave * 32;
  const float* xb = x + (size_t)blockIdx.x * (NT * ND);

  f32x16 aA0, aA1, aA2, aA3, aB0, aB1, aB2, aB3;
#pragma unroll
  for (int e = 0; e < 16; ++e) {
    aA0[e] = 0.f; aA1[e] = 0.f; aA2[e] = 0.f; aA3[e] = 0.f;
    aB0[e] = 0.f; aB1[e] = 0.f; aB2[e] = 0.f; aB3[e] = 0.f;
  }

  f32x4 ld[8];
#pragma unroll
  for (int i = 0; i < 8; ++i)   // prologue: chunk 0 loads
    ld[i] = *(const f32x4*)(xb + (srow + i * 4 + lrow) * ND + lcol * 4);

#pragma unroll 1
  for (int g = 0; g < 4; ++g) {
    u32x4* ckb = &ck[(g & 1) * (NT * 8)];

    // (A) cast + swizzled LDS write of chunk g (waits vmcnt on ld use)
#pragma unroll
    for (int i = 0; i < 8; ++i) {
      const int row = srow + i * 4 + lrow;
      u32x2 o;
      o.x = f2bf_rne(ld[i].x) | (f2bf_rne(ld[i].y) << 16);
      o.y = f2bf_rne(ld[i].z) | (f2bf_rne(ld[i].w) << 16);
      const int slot = (lcol >> 1) ^ (row & 7);
      *(u32x2*)((unsigned int*)(ckb + row * 8 + slot) + (lcol & 1) * 2) = o;
    }

    // (B) issue loads for chunk g+1 (stay in flight across the barrier)
    if (g < 3) {
      const int kc = (g + 1) * 64;
#pragma unroll
      for (int i = 0; i < 8; ++i)
        ld[i] = *(const f32x4*)(xb + (srow + i * 4 + lrow) * ND + kc + lcol * 4);
    }

    // (C) chunk g visible to all waves; vmcnt NOT drained
    wg_barrier();

    // (D) MFMA-accumulate chunk g: 4 k-blocks, shared A-frags, 2 tiles
#pragma unroll
    for (int kb = 0; kb < 4; ++kb) {
      const int ko = ((kb * 2) ^ sx6) | hx;   // swizzled slot
      bf16x8 fa0  = __builtin_bit_cast(bf16x8, ckb[(R + lo5) * 8 + ko]);
      bf16x8 fa1  = __builtin_bit_cast(bf16x8, ckb[(R + 32 + lo5) * 8 + ko]);
      bf16x8 fbA0 = __builtin_bit_cast(bf16x8, ckb[(CA + lo5) * 8 + ko]);
      bf16x8 fbA1 = __builtin_bit_cast(bf16x8, ckb[(CA + 32 + lo5) * 8 + ko]);
      bf16x8 fbB0 = __builtin_bit_cast(bf16x8, ckb[(CB + lo5) * 8 + ko]);
      bf16x8 fbB1 = __builtin_bit_cast(bf16x8, ckb[(CB + 32 + lo5) * 8 + ko]);
      aA0 = MFMA32(fa0, fbA0, aA0, 0, 0, 0);
      aA1 = MFMA32(fa0, fbA1, aA1, 0, 0, 0);
      aA2 = MFMA32(fa1, fbA0, aA2, 0, 0, 0);
      aA3 = MFMA32(fa1, fbA1, aA3, 0, 0, 0);
      aB0 = MFMA32(fa0, fbB0, aB0, 0, 0, 0);
      aB1 = MFMA32(fa0, fbB1, aB1, 0, 0, 0);
      aB2 = MFMA32(fa1, fbB0, aB2, 0, 0, 0);
      aB3 = MFMA32(fa1, fbB1, aB3, 0, 0, 0);
    }
  }

  // ---- batch epilogue -----------------------------------------------------
  // diagonal tiles (waves 0-3, tile A): publish inv = rsqrt(diag)
  if (d == 0) {
    float dv0 = 1.0f, dv1 = 1.0f;
#pragma unroll
    for (int rg = 0; rg < 16; ++rg) {
      const int rowe = (rg & 3) + 8 * (rg >> 2) + 4 * hi;
      if (rowe == lo5) { dv0 = aA0[rg]; dv1 = aA3[rg]; }
    }
    if (hi == ((lo5 >> 2) & 1)) {
      invbuf[R + lo5]      = rsqrtf(fmaxf(dv0, 1e-24f));
      invbuf[R + 32 + lo5] = rsqrtf(fmaxf(dv1, 1e-24f));
    }
  }
  wg_barrier();   // invbuf[256] valid

  // scaled exp column-sums, tile A (cols CA); row==col sum by symmetry
  {
    const float ic0 = invbuf[CA + lo5] * K10L2E;
    const float ic1 = invbuf[CA + 32 + lo5] * K10L2E;
    float e0 = 0.f, e1 = 0.f;
#pragma unroll
    for (int rg = 0; rg < 16; ++rg) {
      const int rowe = (rg & 3) + 8 * (rg >> 2) + 4 * hi;
      const float ir0 = invbuf[R + rowe], ir1 = invbuf[R + 32 + rowe];
      e0 += exp2f(fmaf(aA0[rg] * ir0, ic0, -K10L2E));
      e0 += exp2f(fmaf(aA2[rg] * ir1, ic0, -K10L2E));
      e1 += exp2f(fmaf(aA1[rg] * ir0, ic1, -K10L2E));
      e1 += exp2f(fmaf(aA3[rg] * ir1, ic1, -K10L2E));
    }
    e0 += __shfl_xor(e0, 32);
    e1 += __shfl_xor(e1, 32);
    if (hi == 0) sbuf[CA + lo5][tr] = e0;
    else         sbuf[CA + 32 + lo5][tr] = e1;
  }
  // tile B (cols CB)
  {
    const float ic0 = invbuf[CB + lo5] * K10L2E;
    const float ic1 = invbuf[CB + 32 + lo5] * K10L2E;
    float e0 = 0.f, e1 = 0.f;
#pragma unroll
    for (int rg = 0; rg < 16; ++rg) {
      const int rowe = (rg & 3) + 8 * (rg >> 2) + 4 * hi;
      const float ir0 = invbuf[R + rowe], ir1 = invbuf[R + 32 + rowe];
      e0 += exp2f(fmaf(aB0[rg] * ir0, ic0, -K10L2E));
      e0 += exp2f(fmaf(aB2[rg] * ir1, ic0, -K10L2E));
      e1 += exp2f(fmaf(aB1[rg] * ir0, ic1, -K10L2E));
      e1 += exp2f(fmaf(aB3[rg] * ir1, ic1, -K10L2E));
    }
    e0 += __shfl_xor(e0, 32);
    e1 += __shfl_xor(e1, 32);
    if (hi == 0) sbuf[CB + lo5][tr] = e0;
    else         sbuf[CB + 32 + lo5][tr] = e1;
  }

  // super-diagonal target (only tiles with tr==tcA or tcA==tr+1)
  if (tcA == tr || tcA == tr + 1) {
#pragma unroll
    for (int ar = 0; ar < 2; ++ar) {
#pragma unroll
      for (int rg = 0; rg < 16; ++rg) {
        const int r = R + ar * 32 + (rg & 3) + 8 * (rg >> 2) + 4 * hi;
        const int tcol = r + 1 - CA;
        if (r < NT - 1 && tcol >= 0 && tcol < 64 && lo5 == (tcol & 31)) {
          const float v = (tcol < 32) ? (ar ? aA2[rg] : aA0[rg])
                                      : (ar ? aA3[rg] : aA1[rg]);
          tbuf[r] = 10.0f * v * invbuf[r] * invbuf[r + 1];
        }
      }
    }
  }
  wg_barrier();   // sbuf/tbuf complete

  // merge 4 row-groups per column, subtract target, block-reduce
  float val = 0.0f;
  if (t < NT - 1) {
    const float s = sbuf[t][0] + sbuf[t][1] + sbuf[t][2] + sbuf[t][3];
    val = 10.0f + __logf(s) - tbuf[t];
  }
#pragma unroll
  for (int dd = 1; dd < 64; dd <<= 1) val += __shfl_xor(val, dd);
  if (lane == 0) redbuf[wave] = val;
  wg_barrier();
  if (t == 0) {
    float s = 0.f;
#pragma unroll
    for (int w = 0; w < 8; ++w) s += redbuf[w];
    partial[blockIdx.x] = s;
  }
}

// ---------------- K3: 512 partials -> mean (deterministic) ----------------
__global__ __launch_bounds__(256) void reduce_kernel(
    const float* __restrict__ partial, float* __restrict__ out) {
  const int t = threadIdx.x;
  float v = partial[t] + partial[t + 256];
#pragma unroll
  for (int d = 1; d < 64; d <<= 1) v += __shfl_xor(v, d);
  __shared__ float red[4];
  if ((t & 63) == 0) red[t >> 6] = v;
  __syncthreads();
  if (t == 0)
    out[0] = (red[0] + red[1] + red[2] + red[3]) * (1.0f / (float)(NB * (NT - 1)));
}

extern "C" void kernel_launch(void* const* d_in, const int* in_sizes, int n_in,
                              void* d_out, int out_size, void* d_ws, size_t ws_size,
                              hipStream_t stream) {
  (void)in_sizes; (void)n_in; (void)out_size; (void)ws_size;
  const float* x = (const float*)d_in[0];
  float* out = (float*)d_out;
  float* partial = (float*)d_ws;   // 2 KiB

  hipLaunchKernelGGL(fused_kernel, dim3(NB), dim3(512), 0, stream, x, partial);
  hipLaunchKernelGGL(reduce_kernel, dim3(1), dim3(256), 0, stream, partial, out);
}

// Round 9
// 38.668 us; speedup vs baseline: 12.3567x; 12.3567x over previous
//
#include <hip/hip_runtime.h>

// TemporalContrastiveLoss: B=512, T=256, D=256, temperature 0.1.
// Grid = 256 blocks (1/CU, 512 thr, launch_bounds(512,2) -- 244/256 regs,
// 2 blocks/CU is impossible: 128 acc regs/thread). 2 batches per block.
// S_raw = X*X^T over 16 sub-chunks (32 cols each, 2 batches x 8).
// DEPTH-2 register prefetch: two named sets ldA/ldB alternate; each set is
// consumed two sub-iters after issue -> no vmcnt stall, continuous HBM issue.
// Per sub-iter: {cast fp32->bf16 -> LDS chunk} {issue loads +2} {lgkm barrier}
// {MFMA 2 k-blocks}. Raw s_barrier + lgkmcnt(0) keeps prefetch in flight.
// Epilogue per batch: inv=rsqrt(diag), symmetric column-sum LSE (fixed
// max=10), super-diagonal target; batch-1 prefetch hides under it.
// K3: 512->1 mean.

typedef float f32x4  __attribute__((ext_vector_type(4)));
typedef float f32x16 __attribute__((ext_vector_type(16)));
typedef unsigned int u32x2 __attribute__((ext_vector_type(2)));
typedef unsigned int u32x4 __attribute__((ext_vector_type(4)));
typedef __bf16 bf16x8 __attribute__((ext_vector_type(8)));

#define NB 512
#define NT 256
#define ND 256
#define K10L2E 14.42695041f   // 10 * log2(e)

#define MFMA32 __builtin_amdgcn_mfma_f32_32x32x16_bf16

__device__ __forceinline__ unsigned int f2bf_rne(float f) {
  unsigned int u = __float_as_uint(f);
  return (u + 0x7fffu + ((u >> 16) & 1u)) >> 16;
}

// Barrier that does NOT drain vmcnt (prefetch stays in flight).
__device__ __forceinline__ void wg_barrier() {
  asm volatile("s_waitcnt lgkmcnt(0)" ::: "memory");
  __builtin_amdgcn_s_barrier();
  asm volatile("" ::: "memory");
}

// LDS chunk layout (per 32-col sub-chunk, 16 KiB):
//   [128 double-rows][8 slot16 of 16B]; for row r, logical 8-col slot s:
//   slot16 = ((r&1)*4 + s) ^ ((r>>1)&7)
// -> ds_read_b128 frags and ds_write_b64 staging are both <=2-way (free).
__global__ __launch_bounds__(512, 2) void fused_kernel(
    const float* __restrict__ x, float* __restrict__ partial) {
  __shared__ u32x4 ck[2][128 * 8];   // 2 x 16 KiB sub-chunk double buffer
  __shared__ float invbuf[NT];       // 1/||x_r|| from MFMA diagonal
  __shared__ float sbuf[NT][5];      // per-col, per-64row-group sum exp(p-10)
  __shared__ float tbuf[NT];         // per-row target logit (x10, normalized)
  __shared__ float redbuf[8];

  const int t    = threadIdx.x;
  const int wave = t >> 6;
  const int lane = t & 63;
  const int lo5  = lane & 31;
  const int hi   = lane >> 5;
  const int sxd  = (lo5 >> 1) & 7;   // frag-read row-derived xor
  const int sx4  = (lo5 & 1) * 4;

  // tile assignment: wave w -> tiles (tr, tcA), (tr, tcB); w<4 has diag in A
  const int d   = wave >> 2;
  const int tr  = wave & 3;
  const int tcA = (tr + d) & 3;
  const int tcB = (tr + d + 2) & 3;
  const int R = tr * 64, CA = tcA * 64, CB = tcB * 64;

  // frag base indices (u32x4 units): dr*8; +32 rows => +128
  const int iA  = ((R  + lo5) >> 1) * 8;
  const int iBA = ((CA + lo5) >> 1) * 8;
  const int iBB = ((CB + lo5) >> 1) * 8;

  // staging: wave stages rows wave*32..+31 of each 32-col sub-chunk
  const int j8   = lane >> 3;        // 0..7
  const int c8   = lane & 7;         // 16B (4-fp32) index within 32 cols
  const int s_   = c8 >> 1;          // logical 8-col slot
  const int half = c8 & 1;           // 8B half within slot
  const int srow = wave * 32;

#define ISSUE(SET, TC) do {                                                  \
    const float* bp = x + ((size_t)blockIdx.x + (size_t)((TC) >> 3) * 256)   \
                          * (NT * ND) + ((TC) & 7) * 32;                     \
    _Pragma("unroll")                                                        \
    for (int i = 0; i < 4; ++i)                                              \
      SET[i] = *(const f32x4*)(bp + (srow + i * 8 + j8) * ND + c8 * 4);      \
  } while (0)

#define CAST_WRITE(BUF, SET) do {                                            \
    _Pragma("unroll")                                                        \
    for (int i = 0; i < 4; ++i) {                                            \
      const int r = srow + i * 8 + j8;                                       \
      u32x2 o;                                                               \
      o.x = f2bf_rne(SET[i].x) | (f2bf_rne(SET[i].y) << 16);                 \
      o.y = f2bf_rne(SET[i].z) | (f2bf_rne(SET[i].w) << 16);                 \
      const int slot16 = ((r & 1) * 4 + s_) ^ ((r >> 1) & 7);                \
      *(u32x2*)((unsigned int*)&ck[BUF][0]                                   \
                + ((r >> 1) * 32 + slot16 * 4 + half * 2)) = o;              \
    }                                                                        \
  } while (0)

#define MFMA_CHUNK(BUF) do {                                                 \
    const u32x4* cb = &ck[BUF][0];                                           \
    _Pragma("unroll")                                                        \
    for (int kb = 0; kb < 2; ++kb) {                                         \
      const int ko = (sx4 + kb * 2 + hi) ^ sxd;                              \
      bf16x8 fa0  = __builtin_bit_cast(bf16x8, cb[iA  + ko]);                \
      bf16x8 fa1  = __builtin_bit_cast(bf16x8, cb[iA  + 128 + ko]);          \
      bf16x8 fbA0 = __builtin_bit_cast(bf16x8, cb[iBA + ko]);                \
      bf16x8 fbA1 = __builtin_bit_cast(bf16x8, cb[iBA + 128 + ko]);          \
      bf16x8 fbB0 = __builtin_bit_cast(bf16x8, cb[iBB + ko]);                \
      bf16x8 fbB1 = __builtin_bit_cast(bf16x8, cb[iBB + 128 + ko]);          \
      aA0 = MFMA32(fa0, fbA0, aA0, 0, 0, 0);                                 \
      aA1 = MFMA32(fa0, fbA1, aA1, 0, 0, 0);                                 \
      aA2 = MFMA32(fa1, fbA0, aA2, 0, 0, 0);                                 \
      aA3 = MFMA32(fa1, fbA1, aA3, 0, 0, 0);                                 \
      aB0 = MFMA32(fa0, fbB0, aB0, 0, 0, 0);                                 \
      aB1 = MFMA32(fa0, fbB1, aB1, 0, 0, 0);                                 \
      aB2 = MFMA32(fa1, fbB0, aB2, 0, 0, 0);                                 \
      aB3 = MFMA32(fa1, fbB1, aB3, 0, 0, 0);                                 \
    }                                                                        \
  } while (0)

  f32x16 aA0, aA1, aA2, aA3, aB0, aB1, aB2, aB3;
#pragma unroll
  for (int e = 0; e < 16; ++e) {
    aA0[e] = 0.f; aA1[e] = 0.f; aA2[e] = 0.f; aA3[e] = 0.f;
    aB0[e] = 0.f; aB1[e] = 0.f; aB2[e] = 0.f; aB3[e] = 0.f;
  }

  f32x4 ldA[4], ldB[4];
  ISSUE(ldA, 0);
  ISSUE(ldB, 1);

#pragma unroll 1
  for (int g = 0; g < 16; g += 2) {
    // ---- even sub-chunk g: consume ldA, buf0 ----
    CAST_WRITE(0, ldA);
    if (g + 2 < 16) ISSUE(ldA, g + 2);
    wg_barrier();
    MFMA_CHUNK(0);

    // ---- odd sub-chunk g+1: consume ldB, buf1 ----
    CAST_WRITE(1, ldB);
    if (g + 3 < 16) ISSUE(ldB, g + 3);
    wg_barrier();
    MFMA_CHUNK(1);

    // ---- batch epilogue at g+1 == 7 (batch 0) and 15 (batch 1) ----
    if (((g + 1) & 7) == 7) {
      const int bb = (int)blockIdx.x + ((g + 1) >> 3) * 256;

      // diagonal tiles (waves 0-3, tile A): publish inv = rsqrt(diag)
      if (d == 0) {
        float dv0 = 1.0f, dv1 = 1.0f;
#pragma unroll
        for (int rg = 0; rg < 16; ++rg) {
          const int rowe = (rg & 3) + 8 * (rg >> 2) + 4 * hi;
          if (rowe == lo5) { dv0 = aA0[rg]; dv1 = aA3[rg]; }
        }
        if (hi == ((lo5 >> 2) & 1)) {
          invbuf[R + lo5]      = rsqrtf(fmaxf(dv0, 1e-24f));
          invbuf[R + 32 + lo5] = rsqrtf(fmaxf(dv1, 1e-24f));
        }
      }
      wg_barrier();   // invbuf valid; next-batch prefetch stays in flight

      // scaled exp column-sums (S symmetric: row-LSE sum == column sum)
      {
        const float ic0 = invbuf[CA + lo5] * K10L2E;
        const float ic1 = invbuf[CA + 32 + lo5] * K10L2E;
        float e0 = 0.f, e1 = 0.f;
#pragma unroll
        for (int rg = 0; rg < 16; ++rg) {
          const int rowe = (rg & 3) + 8 * (rg >> 2) + 4 * hi;
          const float ir0 = invbuf[R + rowe], ir1 = invbuf[R + 32 + rowe];
          e0 += exp2f(fmaf(aA0[rg] * ir0, ic0, -K10L2E));
          e0 += exp2f(fmaf(aA2[rg] * ir1, ic0, -K10L2E));
          e1 += exp2f(fmaf(aA1[rg] * ir0, ic1, -K10L2E));
          e1 += exp2f(fmaf(aA3[rg] * ir1, ic1, -K10L2E));
        }
        e0 += __shfl_xor(e0, 32);
        e1 += __shfl_xor(e1, 32);
        if (hi == 0) sbuf[CA + lo5][tr] = e0;
        else         sbuf[CA + 32 + lo5][tr] = e1;
      }
      {
        const float ic0 = invbuf[CB + lo5] * K10L2E;
        const float ic1 = invbuf[CB + 32 + lo5] * K10L2E;
        float e0 = 0.f, e1 = 0.f;
#pragma unroll
        for (int rg = 0; rg < 16; ++rg) {
          const int rowe = (rg & 3) + 8 * (rg >> 2) + 4 * hi;
          const float ir0 = invbuf[R + rowe], ir1 = invbuf[R + 32 + rowe];
          e0 += exp2f(fmaf(aB0[rg] * ir0, ic0, -K10L2E));
          e0 += exp2f(fmaf(aB2[rg] * ir1, ic0, -K10L2E));
          e1 += exp2f(fmaf(aB1[rg] * ir0, ic1, -K10L2E));
          e1 += exp2f(fmaf(aB3[rg] * ir1, ic1, -K10L2E));
        }
        e0 += __shfl_xor(e0, 32);
        e1 += __shfl_xor(e1, 32);
        if (hi == 0) sbuf[CB + lo5][tr] = e0;
        else         sbuf[CB + 32 + lo5][tr] = e1;
      }

      // super-diagonal target (tiles with tcA==tr or tcA==tr+1)
      if (tcA == tr || tcA == tr + 1) {
#pragma unroll
        for (int ar = 0; ar < 2; ++ar) {
#pragma unroll
          for (int rg = 0; rg < 16; ++rg) {
            const int r = R + ar * 32 + (rg & 3) + 8 * (rg >> 2) + 4 * hi;
            const int tcol = r + 1 - CA;
            if (r < NT - 1 && tcol >= 0 && tcol < 64 && lo5 == (tcol & 31)) {
              const float v = (tcol < 32) ? (ar ? aA2[rg] : aA0[rg])
                                          : (ar ? aA3[rg] : aA1[rg]);
              tbuf[r] = 10.0f * v * invbuf[r] * invbuf[r + 1];
            }
          }
        }
      }
      wg_barrier();   // sbuf/tbuf complete

      // merge 4 row-groups per column, subtract target, block-reduce
      float val = 0.0f;
      if (t < NT - 1) {
        const float s = sbuf[t][0] + sbuf[t][1] + sbuf[t][2] + sbuf[t][3];
        val = 10.0f + __logf(s) - tbuf[t];
      }
#pragma unroll
      for (int dd = 1; dd < 64; dd <<= 1) val += __shfl_xor(val, dd);
      if (lane == 0) redbuf[wave] = val;
      wg_barrier();
      if (t == 0) {
        float s = 0.f;
#pragma unroll
        for (int w = 0; w < 8; ++w) s += redbuf[w];
        partial[bb] = s;
      }

      // reset accumulators for next batch
#pragma unroll
      for (int e = 0; e < 16; ++e) {
        aA0[e] = 0.f; aA1[e] = 0.f; aA2[e] = 0.f; aA3[e] = 0.f;
        aB0[e] = 0.f; aB1[e] = 0.f; aB2[e] = 0.f; aB3[e] = 0.f;
      }
    }
  }
#undef ISSUE
#undef CAST_WRITE
#undef MFMA_CHUNK
}

// ---------------- K3: 512 partials -> mean (deterministic) ----------------
__global__ __launch_bounds__(256) void reduce_kernel(
    const float* __restrict__ partial, float* __restrict__ out) {
  const int t = threadIdx.x;
  float v = partial[t] + partial[t + 256];
#pragma unroll
  for (int d = 1; d < 64; d <<= 1) v += __shfl_xor(v, d);
  __shared__ float red[4];
  if ((t & 63) == 0) red[t >> 6] = v;
  __syncthreads();
  if (t == 0)
    out[0] = (red[0] + red[1] + red[2] + red[3]) * (1.0f / (float)(NB * (NT - 1)));
}

extern "C" void kernel_launch(void* const* d_in, const int* in_sizes, int n_in,
                              void* d_out, int out_size, void* d_ws, size_t ws_size,
                              hipStream_t stream) {
  (void)in_sizes; (void)n_in; (void)out_size; (void)ws_size;
  const float* x = (const float*)d_in[0];
  float* out = (float*)d_out;
  float* partial = (float*)d_ws;   // 2 KiB

  hipLaunchKernelGGL(fused_kernel, dim3(NB / 2), dim3(512), 0, stream, x, partial);
  hipLaunchKernelGGL(reduce_kernel, dim3(1), dim3(256), 0, stream, partial, out);
}